// Round 8
// baseline (155.650 us; speedup 1.0000x reference)
//
#include <hip/hip_runtime.h>

#define NB 8
#define NS 4096
#define ND 768

// wpack layout (f4 units):
//   [0,1536)    panel weights  : o*192 + i
//   [1536,4608) dialog weights : o*384 + i  (+192 = parent half)
//   [4608,6144) char weights   : o*384 + i  (+192 = parent half)
//   [6144,6336) lng | [6336,6528) lnb
#define WPACK_F4 6528

// lp_main LDS (f4 units): [0,3072) role weights | [3072,3264) lng
//   | [3264,3456) lnb | [3456,3648) sprj row
#define MAIN_LDS_F4 3648

typedef float4 f4;

static __device__ __forceinline__ f4 ld4(const float* __restrict__ p, int i) {
    return ((const f4*)p)[i];
}

static __device__ __forceinline__ void dot4(float& acc, const f4& a, const f4& w) {
    acc = fmaf(a.x, w.x, acc);
    acc = fmaf(a.y, w.y, acc);
    acc = fmaf(a.z, w.z, acc);
    acc = fmaf(a.w, w.w, acc);
}

// ---------------------------------------------------------------------------
// Kernel 1 (lp_pre):
//   blocks   0..127 : scatter-max parent table (stores seqpos+1; 0 = none)
//                     + per-(type,batch) token-list append (ballot/popc,
//                     one atomicAdd per wave per type)
//   blocks 128..129 : per-batch style projection (8 waves)
//   blocks 130..155 : pack head weights + ln params into wpack
// ---------------------------------------------------------------------------
__global__ __launch_bounds__(256) void lp_pre(
    const int* __restrict__ et, const int* __restrict__ ei,
    const float* __restrict__ sv, const float* __restrict__ sw,
    const float* __restrict__ sb,
    const float* __restrict__ pw, const float* __restrict__ dw,
    const float* __restrict__ cw,
    const float* __restrict__ lng, const float* __restrict__ lnb,
    int* __restrict__ table, int* __restrict__ cnt, int* __restrict__ lists,
    float* __restrict__ sprj, float* __restrict__ wpack)
{
    const int bx = blockIdx.x;
    if (bx < 128) {
        const int lane = threadIdx.x & 63;
        const int t = bx * 256 + threadIdx.x;
        const int b = t >> 12;                       // block-uniform (256|4096)
        const int s = t & (NS - 1);
        const int type = et[t];
        if (type == 1) atomicMax(&table[b * 64 + ei[t]], s + 1);
        #pragma unroll
        for (int role = 0; role < 3; ++role) {
            const int want = (type == role + 1);
            unsigned long long m = __ballot(want);
            if (want) {
                int ldr = __ffsll(m) - 1;
                int base = 0;
                if (lane == ldr) base = atomicAdd(&cnt[role * 8 + b], (int)__popcll(m));
                base = __shfl(base, ldr, 64);
                int pos = (int)__popcll(m & ((1ull << lane) - 1));
                lists[(role * 8 + b) * 4096 + base + pos] = s;
            }
        }
    } else if (bx < 130) {
        const int lane = threadIdx.x & 63;
        const int b = (bx - 128) * 4 + (threadIdx.x >> 6);   // 0..7
        const float sv0 = sv[b*4+0], sv1 = sv[b*4+1], sv2 = sv[b*4+2], sv3 = sv[b*4+3];
        #pragma unroll
        for (int g = 0; g < 3; ++g) {
            int i = g*64 + lane;
            f4 w0 = ld4(sw, i), w1 = ld4(sw, 192+i), w2 = ld4(sw, 384+i), w3 = ld4(sw, 576+i);
            f4 bb = ld4(sb, i);
            f4 r;
            r.x = bb.x + sv0*w0.x + sv1*w1.x + sv2*w2.x + sv3*w3.x;
            r.y = bb.y + sv0*w0.y + sv1*w1.y + sv2*w2.y + sv3*w3.y;
            r.z = bb.z + sv0*w0.z + sv1*w1.z + sv2*w2.z + sv3*w3.z;
            r.w = bb.w + sv0*w0.w + sv1*w1.w + sv2*w2.w + sv3*w3.w;
            ((f4*)(sprj + b*ND))[i] = r;
        }
    } else {
        const int q = (bx - 130) * 256 + threadIdx.x;   // 0..6655
        if (q >= WPACK_F4) return;
        f4 r;
        if (q < 1536) {                                  // panel: 8 x 192
            int o = q / 192, i = q - o * 192, d0 = 4 * i;
            r.x = pw[(d0+0)*8 + o];
            r.y = pw[(d0+1)*8 + o];
            r.z = pw[(d0+2)*8 + o];
            r.w = pw[(d0+3)*8 + o];
        } else if (q < 4608) {                           // dialog: 8 x 384
            int u = q - 1536;
            int o = u / 384, i = u - o * 384;
            int d0 = (i < 192) ? 4*i : 768 + 4*(i - 192);
            r.x = dw[(d0+0)*8 + o];
            r.y = dw[(d0+1)*8 + o];
            r.z = dw[(d0+2)*8 + o];
            r.w = dw[(d0+3)*8 + o];
        } else if (q < 6144) {                           // char: 4 x 384
            int u = q - 4608;
            int o = u / 384, i = u - o * 384;
            int d0 = (i < 192) ? 4*i : 768 + 4*(i - 192);
            r.x = cw[(d0+0)*4 + o];
            r.y = cw[(d0+1)*4 + o];
            r.z = cw[(d0+2)*4 + o];
            r.w = cw[(d0+3)*4 + o];
        } else if (q < 6336) {                           // lng
            r = ld4(lng, q - 6144);
        } else {                                         // lnb
            r = ld4(lnb, q - 6336);
        }
        ((f4*)wpack)[q] = r;
    }
}

// ---------------------------------------------------------------------------
// Kernel 2 (lp_parent): one wave per (b, slot); NORMALIZED parent feats.
// ---------------------------------------------------------------------------
__global__ __launch_bounds__(256) void lp_parent(
    const int* __restrict__ ei, const int* __restrict__ ppi,
    const float* __restrict__ temb, const float* __restrict__ iemb,
    const float* __restrict__ pemb, const float* __restrict__ lng,
    const float* __restrict__ lnb,
    const int* __restrict__ table, const float* __restrict__ sprj,
    float* __restrict__ pfeat)
{
    const int lane = threadIdx.x & 63;
    const int slot = blockIdx.x * 4 + (threadIdx.x >> 6);   // 0..511
    const int b = slot >> 6;
    const int pp = table[slot] - 1;                         // +1 encoding
    if (pp < 0) return;                                     // wave-uniform
    const int ptok = b * NS + pp;
    const int pei = ei[ptok], pppi = ppi[ptok];
    const float* ie = iemb + pei * ND;
    const float* pe = pemb + pppi * ND;
    const float* sp = sprj + b * ND;

    f4 x[3]; float s1 = 0.f, sq = 0.f;
    #pragma unroll
    for (int g = 0; g < 3; ++g) {
        int i = g*64 + lane;
        f4 a = ld4(temb + ND, i), c = ld4(ie, i), d = ld4(pe, i), s = ld4(sp, i);
        f4 v;
        v.x = a.x + c.x + d.x + s.x;
        v.y = a.y + c.y + d.y + s.y;
        v.z = a.z + c.z + d.z + s.z;
        v.w = a.w + c.w + d.w + s.w;
        x[g] = v;
        s1 += v.x + v.y + v.z + v.w;
        sq = fmaf(v.x, v.x, sq);
        sq = fmaf(v.y, v.y, sq);
        sq = fmaf(v.z, v.z, sq);
        sq = fmaf(v.w, v.w, sq);
    }
    #pragma unroll
    for (int k = 32; k >= 1; k >>= 1) {
        s1 += __shfl_xor(s1, k, 64);
        sq += __shfl_xor(sq, k, 64);
    }
    float mu = s1 * (1.f/ND);
    float rs = rsqrtf(sq * (1.f/ND) - mu * mu + 1e-5f);
    float c0 = -mu * rs;
    float* dst = pfeat + (size_t)slot * ND;
    #pragma unroll
    for (int g = 0; g < 3; ++g) {
        int i = g*64 + lane;
        f4 gg = ld4(lng, i), bb = ld4(lnb, i);
        f4 v = x[g], xn;
        xn.x = fmaf(v.x, rs, c0); v.x = fmaf(xn.x, gg.x, bb.x);
        xn.y = fmaf(v.y, rs, c0); v.y = fmaf(xn.y, gg.y, bb.y);
        xn.z = fmaf(v.z, rs, c0); v.z = fmaf(xn.z, gg.z, bb.z);
        xn.w = fmaf(v.w, rs, c0); v.w = fmaf(xn.w, gg.w, bb.w);
        ((f4*)dst)[i] = v;
    }
}

// ---------------------------------------------------------------------------
// Kernel 3 (lp_main): type-compacted, role-specialized.
//   512 blocks x 1024 threads; per batch: 16 panel + 32 dialog + 16 char
//   blocks. Each block stages ONLY its role's weights + ln + its batch's
//   sprj row: 58,368 B LDS -> 2 blocks/CU; __launch_bounds__(1024,8) pins
//   VGPR <= 64 -> 32 waves/CU. Waves walk the (type,batch) token list;
//   type-0 and invalid-parent tokens are never visited (out pre-zeroed).
//   Dialog/char use the round-3 phase split (x reused for parent feats).
// ---------------------------------------------------------------------------
__global__ __launch_bounds__(1024, 8) void lp_main(
    const int* __restrict__ ei, const int* __restrict__ ppi,
    const float* __restrict__ temb, const float* __restrict__ iemb,
    const float* __restrict__ pemb,
    const float* __restrict__ pb, const float* __restrict__ db,
    const float* __restrict__ cb,
    const int* __restrict__ table, const int* __restrict__ cnt,
    const int* __restrict__ lists, const float* __restrict__ sprj,
    const float* __restrict__ wpack, const float* __restrict__ pfeat,
    float* __restrict__ out)
{
    __shared__ f4 S[MAIN_LDS_F4];            // 58,368 B -> 2 blocks/CU
    const int tid = threadIdx.x;
    const int lane = tid & 63;
    const int wid = tid >> 6;                // 0..15
    const int bx = blockIdx.x;               // 0..511
    const int b = bx >> 6;                   // 64 blocks per batch
    const int r = bx & 63;

    int role, ridx, nb, wbase, wcnt;
    if (r < 16)      { role = 0; ridx = r;      nb = 16; wbase = 0;    wcnt = 1536; }
    else if (r < 48) { role = 1; ridx = r - 16; nb = 32; wbase = 1536; wcnt = 3072; }
    else             { role = 2; ridx = r - 48; nb = 16; wbase = 4608; wcnt = 1536; }

    // ---- stage role weights + ln + this batch's style row ----
    const f4* wsrc = (const f4*)wpack;
    for (int i = tid; i < wcnt; i += 1024) S[i] = wsrc[wbase + i];
    if (tid < 384) S[3072 + tid] = wsrc[6144 + tid];          // lng, lnb
    if (tid < 192) S[3456 + tid] = ((const f4*)(sprj + b * ND))[tid];
    __syncthreads();

    const int n = cnt[role * 8 + b];
    const int* lst = lists + (role * 8 + b) * 4096;
    const int tb = b * NS;
    const int step = nb * 16;
    const float* te = temb + (role + 1) * ND;

    for (int i = ridx * 16 + wid; i < n; i += step) {
        const int s = lst[i];
        const int t = tb + s;
        const int my_ei = ei[t], my_ppi = ppi[t];

        int pp = 0;
        if (role != 0) {
            pp = table[b * 64 + my_ppi] - 1;
            if (pp < 0) continue;                // out pre-zeroed
        }

        const float* ie = iemb + my_ei * ND;
        const float* pe = pemb + my_ppi * ND;

        // --- own feats: embedding sum + style proj, single-pass stats ---
        f4 x[3];
        float s1 = 0.f, sq = 0.f;
        #pragma unroll
        for (int g = 0; g < 3; ++g) {
            int ii = g * 64 + lane;
            f4 a = ld4(te, ii), c = ld4(ie, ii), d = ld4(pe, ii);
            f4 sp = S[3456 + ii];
            f4 v;
            v.x = a.x + c.x + d.x + sp.x;
            v.y = a.y + c.y + d.y + sp.y;
            v.z = a.z + c.z + d.z + sp.z;
            v.w = a.w + c.w + d.w + sp.w;
            x[g] = v;
            s1 += v.x + v.y + v.z + v.w;
            sq = fmaf(v.x, v.x, sq);
            sq = fmaf(v.y, v.y, sq);
            sq = fmaf(v.z, v.z, sq);
            sq = fmaf(v.w, v.w, sq);
        }
        #pragma unroll
        for (int k = 32; k >= 1; k >>= 1) {
            s1 += __shfl_xor(s1, k, 64);
            sq += __shfl_xor(sq, k, 64);
        }
        float mu = s1 * (1.f / ND);
        float rs = rsqrtf(sq * (1.f / ND) - mu * mu + 1e-5f);
        float c0 = -mu * rs;
        #pragma unroll
        for (int g = 0; g < 3; ++g) {
            int ii = g * 64 + lane;
            f4 gg = S[3072 + ii], bb = S[3264 + ii];
            f4 v = x[g], xn;
            xn.x = fmaf(v.x, rs, c0); v.x = fmaf(xn.x, gg.x, bb.x);
            xn.y = fmaf(v.y, rs, c0); v.y = fmaf(xn.y, gg.y, bb.y);
            xn.z = fmaf(v.z, rs, c0); v.z = fmaf(xn.z, gg.z, bb.z);
            xn.w = fmaf(v.w, rs, c0); v.w = fmaf(xn.w, gg.w, bb.w);
            x[g] = v;
        }

        if (role == 0) {
            float acc[8];
            #pragma unroll
            for (int o = 0; o < 8; ++o) acc[o] = 0.f;
            #pragma unroll
            for (int g = 0; g < 3; ++g) {
                int ii = g * 64 + lane;
                #pragma unroll
                for (int o = 0; o < 8; ++o)
                    dot4(acc[o], x[g], S[o * 192 + ii]);
            }
            #pragma unroll
            for (int k = 32; k >= 1; k >>= 1) {
                #pragma unroll
                for (int o = 0; o < 8; ++o)
                    acc[o] += __shfl_xor(acc[o], k, 64);
            }
            if (lane == 0) {
                f4 r0, r1;
                r0.x = acc[0] + pb[0]; r0.y = acc[1] + pb[1];
                r0.z = acc[2] + pb[2]; r0.w = acc[3] + pb[3];
                r1.x = acc[4] + pb[4]; r1.y = acc[5] + pb[5];
                r1.z = acc[6] + pb[6]; r1.w = acc[7] + pb[7];
                f4* op = (f4*)(out + (size_t)t * 8);
                op[0] = r0; op[1] = r1;
            }
        } else {
            const float* pfr = pfeat + (size_t)(b * 64 + my_ppi) * ND;
            if (role == 1) {
                float acc[8];
                #pragma unroll
                for (int o = 0; o < 8; ++o) acc[o] = 0.f;
                // phase A: own feats vs cols [0,768)
                #pragma unroll
                for (int g = 0; g < 3; ++g) {
                    int ii = g * 64 + lane;
                    #pragma unroll
                    for (int o = 0; o < 8; ++o)
                        dot4(acc[o], x[g], S[o * 384 + ii]);
                }
                // parent feats (pre-normalized) overwrite x
                #pragma unroll
                for (int g = 0; g < 3; ++g)
                    x[g] = ld4(pfr, g * 64 + lane);
                // phase B: parent feats vs cols [768,1536)
                #pragma unroll
                for (int g = 0; g < 3; ++g) {
                    int ii = g * 64 + lane;
                    #pragma unroll
                    for (int o = 0; o < 8; ++o)
                        dot4(acc[o], x[g], S[o * 384 + 192 + ii]);
                }
                #pragma unroll
                for (int k = 32; k >= 1; k >>= 1) {
                    #pragma unroll
                    for (int o = 0; o < 8; ++o)
                        acc[o] += __shfl_xor(acc[o], k, 64);
                }
                if (lane == 0) {
                    f4 r0, r1;
                    r0.x = acc[0] + db[0]; r0.y = acc[1] + db[1];
                    r0.z = acc[2] + db[2]; r0.w = acc[3] + db[3];
                    r1.x = acc[4] + db[4]; r1.y = acc[5] + db[5];
                    r1.z = acc[6] + db[6]; r1.w = acc[7] + db[7];
                    f4* od = (f4*)(out + (size_t)NB * NS * 8 + (size_t)t * 8);
                    od[0] = r0; od[1] = r1;
                }
            } else {
                float acc[4];
                #pragma unroll
                for (int o = 0; o < 4; ++o) acc[o] = 0.f;
                #pragma unroll
                for (int g = 0; g < 3; ++g) {
                    int ii = g * 64 + lane;
                    #pragma unroll
                    for (int o = 0; o < 4; ++o)
                        dot4(acc[o], x[g], S[o * 384 + ii]);
                }
                #pragma unroll
                for (int g = 0; g < 3; ++g)
                    x[g] = ld4(pfr, g * 64 + lane);
                #pragma unroll
                for (int g = 0; g < 3; ++g) {
                    int ii = g * 64 + lane;
                    #pragma unroll
                    for (int o = 0; o < 4; ++o)
                        dot4(acc[o], x[g], S[o * 384 + 192 + ii]);
                }
                #pragma unroll
                for (int k = 32; k >= 1; k >>= 1) {
                    #pragma unroll
                    for (int o = 0; o < 4; ++o)
                        acc[o] += __shfl_xor(acc[o], k, 64);
                }
                if (lane == 0) {
                    f4 r0;
                    r0.x = acc[0] + cb[0]; r0.y = acc[1] + cb[1];
                    r0.z = acc[2] + cb[2]; r0.w = acc[3] + cb[3];
                    ((f4*)(out + (size_t)NB * NS * 16 + (size_t)t * 4))[0] = r0;
                }
            }
        }
    }
}

extern "C" void kernel_launch(void* const* d_in, const int* in_sizes, int n_in,
                              void* d_out, int out_size, void* d_ws, size_t ws_size,
                              hipStream_t stream) {
    const int* et  = (const int*)d_in[0];
    const int* ei  = (const int*)d_in[1];
    const int* ppi = (const int*)d_in[2];
    const float* sv   = (const float*)d_in[3];
    const float* temb = (const float*)d_in[4];
    const float* iemb = (const float*)d_in[5];
    const float* pemb = (const float*)d_in[6];
    const float* sw   = (const float*)d_in[7];
    const float* sb   = (const float*)d_in[8];
    const float* lng  = (const float*)d_in[9];
    const float* lnb  = (const float*)d_in[10];
    const float* pw   = (const float*)d_in[11];
    const float* pb   = (const float*)d_in[12];
    const float* dw   = (const float*)d_in[13];
    const float* db   = (const float*)d_in[14];
    const float* cw   = (const float*)d_in[15];
    const float* cbp  = (const float*)d_in[16];
    float* out = (float*)d_out;

    // ws layout:
    //   [0,2048)        table (stores seqpos+1; 0 = none)
    //   [2048,2144)     cnt[3][8]
    //   [4096,28672)    sprj (8x768 f32)
    //   [32768,+104448) wpack (6528 f4)
    //   [137216,+384KB) lists (3 x 8 x 4096 ints)
    //   [532480,+1.5MB) pfeat (512x768 f32)
    int*   table = (int*)d_ws;
    int*   cnt   = (int*)((char*)d_ws + 2048);
    float* sprj  = (float*)((char*)d_ws + 4096);
    float* wpack = (float*)((char*)d_ws + 32768);
    int*   lists = (int*)((char*)d_ws + 137216);
    float* pfeat = (float*)((char*)d_ws + 532480);

    hipMemsetAsync(d_ws, 0, 2144, stream);           // table (+1 enc) + counts
    hipMemsetAsync(d_out, 0, out_size, stream);      // masked rows = 0

    lp_pre<<<156, 256, 0, stream>>>(et, ei, sv, sw, sb, pw, dw, cw, lng, lnb,
                                    table, cnt, lists, sprj, wpack);
    lp_parent<<<128, 256, 0, stream>>>(ei, ppi, temb, iemb, pemb, lng, lnb,
                                       table, sprj, pfeat);
    lp_main<<<512, 1024, 0, stream>>>(ei, ppi, temb, iemb, pemb,
                                      pb, db, cbp,
                                      table, cnt, lists, sprj, wpack, pfeat,
                                      out);
}

// Round 9
// 152.123 us; speedup vs baseline: 1.0232x; 1.0232x over previous
//
#include <hip/hip_runtime.h>

#define NB 8
#define NS 4096
#define ND 768

// wpack layout (f4 units):
//   [0,1536)    panel weights  : o*192 + i
//   [1536,4608) dialog weights : o*384 + i  (+192 = parent half)
//   [4608,6144) char weights   : o*384 + i  (+192 = parent half)
//   [6144,6336) lng | [6336,6528) lnb
#define WPACK_F4 6528

// lp_main LDS (f4 units): [0,3072) role weights | [3072,3264) lng
//   | [3264,3456) lnb | [3456,3648) sprj row
#define MAIN_LDS_F4 3648

typedef float4 f4;

static __device__ __forceinline__ f4 ld4(const float* __restrict__ p, int i) {
    return ((const f4*)p)[i];
}

static __device__ __forceinline__ void dot4(float& acc, const f4& a, const f4& w) {
    acc = fmaf(a.x, w.x, acc);
    acc = fmaf(a.y, w.y, acc);
    acc = fmaf(a.z, w.z, acc);
    acc = fmaf(a.w, w.w, acc);
}

// ---------------------------------------------------------------------------
// Kernel 1 (lp_pre):
//   blocks   0..127 : scatter-max parent table (stores seqpos+1; 0 = none)
//                     + per-(type,batch) token-list append (ballot/popc,
//                     one atomicAdd per wave per type)
//   blocks 128..129 : per-batch style projection (8 waves)
//   blocks 130..155 : pack head weights + ln params into wpack
// ---------------------------------------------------------------------------
__global__ __launch_bounds__(256) void lp_pre(
    const int* __restrict__ et, const int* __restrict__ ei,
    const float* __restrict__ sv, const float* __restrict__ sw,
    const float* __restrict__ sb,
    const float* __restrict__ pw, const float* __restrict__ dw,
    const float* __restrict__ cw,
    const float* __restrict__ lng, const float* __restrict__ lnb,
    int* __restrict__ table, int* __restrict__ cnt, int* __restrict__ lists,
    float* __restrict__ sprj, float* __restrict__ wpack)
{
    const int bx = blockIdx.x;
    if (bx < 128) {
        const int lane = threadIdx.x & 63;
        const int t = bx * 256 + threadIdx.x;
        const int b = t >> 12;                       // block-uniform (256|4096)
        const int s = t & (NS - 1);
        const int type = et[t];
        if (type == 1) atomicMax(&table[b * 64 + ei[t]], s + 1);
        #pragma unroll
        for (int role = 0; role < 3; ++role) {
            const int want = (type == role + 1);
            unsigned long long m = __ballot(want);
            if (want) {
                int ldr = __ffsll(m) - 1;
                int base = 0;
                if (lane == ldr) base = atomicAdd(&cnt[role * 8 + b], (int)__popcll(m));
                base = __shfl(base, ldr, 64);
                int pos = (int)__popcll(m & ((1ull << lane) - 1));
                lists[(role * 8 + b) * 4096 + base + pos] = s;
            }
        }
    } else if (bx < 130) {
        const int lane = threadIdx.x & 63;
        const int b = (bx - 128) * 4 + (threadIdx.x >> 6);   // 0..7
        const float sv0 = sv[b*4+0], sv1 = sv[b*4+1], sv2 = sv[b*4+2], sv3 = sv[b*4+3];
        #pragma unroll
        for (int g = 0; g < 3; ++g) {
            int i = g*64 + lane;
            f4 w0 = ld4(sw, i), w1 = ld4(sw, 192+i), w2 = ld4(sw, 384+i), w3 = ld4(sw, 576+i);
            f4 bb = ld4(sb, i);
            f4 r;
            r.x = bb.x + sv0*w0.x + sv1*w1.x + sv2*w2.x + sv3*w3.x;
            r.y = bb.y + sv0*w0.y + sv1*w1.y + sv2*w2.y + sv3*w3.y;
            r.z = bb.z + sv0*w0.z + sv1*w1.z + sv2*w2.z + sv3*w3.z;
            r.w = bb.w + sv0*w0.w + sv1*w1.w + sv2*w2.w + sv3*w3.w;
            ((f4*)(sprj + b*ND))[i] = r;
        }
    } else {
        const int q = (bx - 130) * 256 + threadIdx.x;   // 0..6655
        if (q >= WPACK_F4) return;
        f4 r;
        if (q < 1536) {                                  // panel: 8 x 192
            int o = q / 192, i = q - o * 192, d0 = 4 * i;
            r.x = pw[(d0+0)*8 + o];
            r.y = pw[(d0+1)*8 + o];
            r.z = pw[(d0+2)*8 + o];
            r.w = pw[(d0+3)*8 + o];
        } else if (q < 4608) {                           // dialog: 8 x 384
            int u = q - 1536;
            int o = u / 384, i = u - o * 384;
            int d0 = (i < 192) ? 4*i : 768 + 4*(i - 192);
            r.x = dw[(d0+0)*8 + o];
            r.y = dw[(d0+1)*8 + o];
            r.z = dw[(d0+2)*8 + o];
            r.w = dw[(d0+3)*8 + o];
        } else if (q < 6144) {                           // char: 4 x 384
            int u = q - 4608;
            int o = u / 384, i = u - o * 384;
            int d0 = (i < 192) ? 4*i : 768 + 4*(i - 192);
            r.x = cw[(d0+0)*4 + o];
            r.y = cw[(d0+1)*4 + o];
            r.z = cw[(d0+2)*4 + o];
            r.w = cw[(d0+3)*4 + o];
        } else if (q < 6336) {                           // lng
            r = ld4(lng, q - 6144);
        } else {                                         // lnb
            r = ld4(lnb, q - 6336);
        }
        ((f4*)wpack)[q] = r;
    }
}

// ---------------------------------------------------------------------------
// Kernel 2 (lp_parent): one wave per (b, slot); NORMALIZED parent feats.
// ---------------------------------------------------------------------------
__global__ __launch_bounds__(256) void lp_parent(
    const int* __restrict__ ei, const int* __restrict__ ppi,
    const float* __restrict__ temb, const float* __restrict__ iemb,
    const float* __restrict__ pemb, const float* __restrict__ lng,
    const float* __restrict__ lnb,
    const int* __restrict__ table, const float* __restrict__ sprj,
    float* __restrict__ pfeat)
{
    const int lane = threadIdx.x & 63;
    const int slot = blockIdx.x * 4 + (threadIdx.x >> 6);   // 0..511
    const int b = slot >> 6;
    const int pp = table[slot] - 1;                         // +1 encoding
    if (pp < 0) return;                                     // wave-uniform
    const int ptok = b * NS + pp;
    const int pei = ei[ptok], pppi = ppi[ptok];
    const float* ie = iemb + pei * ND;
    const float* pe = pemb + pppi * ND;
    const float* sp = sprj + b * ND;

    f4 x[3]; float s1 = 0.f, sq = 0.f;
    #pragma unroll
    for (int g = 0; g < 3; ++g) {
        int i = g*64 + lane;
        f4 a = ld4(temb + ND, i), c = ld4(ie, i), d = ld4(pe, i), s = ld4(sp, i);
        f4 v;
        v.x = a.x + c.x + d.x + s.x;
        v.y = a.y + c.y + d.y + s.y;
        v.z = a.z + c.z + d.z + s.z;
        v.w = a.w + c.w + d.w + s.w;
        x[g] = v;
        s1 += v.x + v.y + v.z + v.w;
        sq = fmaf(v.x, v.x, sq);
        sq = fmaf(v.y, v.y, sq);
        sq = fmaf(v.z, v.z, sq);
        sq = fmaf(v.w, v.w, sq);
    }
    #pragma unroll
    for (int k = 32; k >= 1; k >>= 1) {
        s1 += __shfl_xor(s1, k, 64);
        sq += __shfl_xor(sq, k, 64);
    }
    float mu = s1 * (1.f/ND);
    float rs = rsqrtf(sq * (1.f/ND) - mu * mu + 1e-5f);
    float c0 = -mu * rs;
    float* dst = pfeat + (size_t)slot * ND;
    #pragma unroll
    for (int g = 0; g < 3; ++g) {
        int i = g*64 + lane;
        f4 gg = ld4(lng, i), bb = ld4(lnb, i);
        f4 v = x[g], xn;
        xn.x = fmaf(v.x, rs, c0); v.x = fmaf(xn.x, gg.x, bb.x);
        xn.y = fmaf(v.y, rs, c0); v.y = fmaf(xn.y, gg.y, bb.y);
        xn.z = fmaf(v.z, rs, c0); v.z = fmaf(xn.z, gg.z, bb.z);
        xn.w = fmaf(v.w, rs, c0); v.w = fmaf(xn.w, gg.w, bb.w);
        ((f4*)dst)[i] = v;
    }
}

// ---------------------------------------------------------------------------
// Kernel 3 (lp_main): type-compacted, role-specialized.
//   512 blocks x 1024 threads; per batch: 16 panel + 32 dialog + 16 char
//   blocks. Each block stages ONLY its role's weights + ln + its batch's
//   sprj row: 58,368 B LDS -> 2 blocks/CU.
//   __launch_bounds__(1024) with NO min-waves hint: the natural allocation
//   for this pipeline is ~60 VGPR (rounds 3/5), which already satisfies the
//   8-waves/SIMD budget (<=64) -> 32 waves/CU with no spills. (Round 8's
//   (1024,8) hint clamped to 32 VGPR and spilled 25 MB/dispatch.)
//   Waves walk the (type,batch) token list; type-0 and invalid-parent
//   tokens never visited (out pre-zeroed). Dialog/char reuse x for parent
//   feats (phase split) to stay under the 64-VGPR cliff.
// ---------------------------------------------------------------------------
__global__ __launch_bounds__(1024) void lp_main(
    const int* __restrict__ ei, const int* __restrict__ ppi,
    const float* __restrict__ temb, const float* __restrict__ iemb,
    const float* __restrict__ pemb,
    const float* __restrict__ pb, const float* __restrict__ db,
    const float* __restrict__ cb,
    const int* __restrict__ table, const int* __restrict__ cnt,
    const int* __restrict__ lists, const float* __restrict__ sprj,
    const float* __restrict__ wpack, const float* __restrict__ pfeat,
    float* __restrict__ out)
{
    __shared__ f4 S[MAIN_LDS_F4];            // 58,368 B -> 2 blocks/CU
    const int tid = threadIdx.x;
    const int lane = tid & 63;
    const int wid = tid >> 6;                // 0..15
    const int bx = blockIdx.x;               // 0..511
    const int b = bx >> 6;                   // 64 blocks per batch
    const int r = bx & 63;

    int role, ridx, nb, wbase, wcnt;
    if (r < 16)      { role = 0; ridx = r;      nb = 16; wbase = 0;    wcnt = 1536; }
    else if (r < 48) { role = 1; ridx = r - 16; nb = 32; wbase = 1536; wcnt = 3072; }
    else             { role = 2; ridx = r - 48; nb = 16; wbase = 4608; wcnt = 1536; }

    // ---- stage role weights + ln + this batch's style row ----
    const f4* wsrc = (const f4*)wpack;
    for (int i = tid; i < wcnt; i += 1024) S[i] = wsrc[wbase + i];
    if (tid < 384) S[3072 + tid] = wsrc[6144 + tid];          // lng, lnb
    if (tid < 192) S[3456 + tid] = ((const f4*)(sprj + b * ND))[tid];
    __syncthreads();

    const int n = cnt[role * 8 + b];
    const int* lst = lists + (role * 8 + b) * 4096;
    const int tb = b * NS;
    const int step = nb * 16;
    const float* te = temb + (role + 1) * ND;

    for (int i = ridx * 16 + wid; i < n; i += step) {
        const int s = lst[i];
        const int t = tb + s;
        const int my_ei = ei[t], my_ppi = ppi[t];

        int pp = 0;
        if (role != 0) {
            pp = table[b * 64 + my_ppi] - 1;
            if (pp < 0) continue;                // out pre-zeroed
        }

        const float* ie = iemb + my_ei * ND;
        const float* pe = pemb + my_ppi * ND;

        // --- own feats: embedding sum + style proj, single-pass stats ---
        f4 x[3];
        float s1 = 0.f, sq = 0.f;
        #pragma unroll
        for (int g = 0; g < 3; ++g) {
            int ii = g * 64 + lane;
            f4 a = ld4(te, ii), c = ld4(ie, ii), d = ld4(pe, ii);
            f4 sp = S[3456 + ii];
            f4 v;
            v.x = a.x + c.x + d.x + sp.x;
            v.y = a.y + c.y + d.y + sp.y;
            v.z = a.z + c.z + d.z + sp.z;
            v.w = a.w + c.w + d.w + sp.w;
            x[g] = v;
            s1 += v.x + v.y + v.z + v.w;
            sq = fmaf(v.x, v.x, sq);
            sq = fmaf(v.y, v.y, sq);
            sq = fmaf(v.z, v.z, sq);
            sq = fmaf(v.w, v.w, sq);
        }
        #pragma unroll
        for (int k = 32; k >= 1; k >>= 1) {
            s1 += __shfl_xor(s1, k, 64);
            sq += __shfl_xor(sq, k, 64);
        }
        float mu = s1 * (1.f / ND);
        float rs = rsqrtf(sq * (1.f / ND) - mu * mu + 1e-5f);
        float c0 = -mu * rs;
        #pragma unroll
        for (int g = 0; g < 3; ++g) {
            int ii = g * 64 + lane;
            f4 gg = S[3072 + ii], bb = S[3264 + ii];
            f4 v = x[g], xn;
            xn.x = fmaf(v.x, rs, c0); v.x = fmaf(xn.x, gg.x, bb.x);
            xn.y = fmaf(v.y, rs, c0); v.y = fmaf(xn.y, gg.y, bb.y);
            xn.z = fmaf(v.z, rs, c0); v.z = fmaf(xn.z, gg.z, bb.z);
            xn.w = fmaf(v.w, rs, c0); v.w = fmaf(xn.w, gg.w, bb.w);
            x[g] = v;
        }

        if (role == 0) {
            float acc[8];
            #pragma unroll
            for (int o = 0; o < 8; ++o) acc[o] = 0.f;
            #pragma unroll
            for (int g = 0; g < 3; ++g) {
                int ii = g * 64 + lane;
                #pragma unroll
                for (int o = 0; o < 8; ++o)
                    dot4(acc[o], x[g], S[o * 192 + ii]);
            }
            #pragma unroll
            for (int k = 32; k >= 1; k >>= 1) {
                #pragma unroll
                for (int o = 0; o < 8; ++o)
                    acc[o] += __shfl_xor(acc[o], k, 64);
            }
            if (lane == 0) {
                f4 r0, r1;
                r0.x = acc[0] + pb[0]; r0.y = acc[1] + pb[1];
                r0.z = acc[2] + pb[2]; r0.w = acc[3] + pb[3];
                r1.x = acc[4] + pb[4]; r1.y = acc[5] + pb[5];
                r1.z = acc[6] + pb[6]; r1.w = acc[7] + pb[7];
                f4* op = (f4*)(out + (size_t)t * 8);
                op[0] = r0; op[1] = r1;
            }
        } else {
            const float* pfr = pfeat + (size_t)(b * 64 + my_ppi) * ND;
            if (role == 1) {
                float acc[8];
                #pragma unroll
                for (int o = 0; o < 8; ++o) acc[o] = 0.f;
                // phase A: own feats vs cols [0,768)
                #pragma unroll
                for (int g = 0; g < 3; ++g) {
                    int ii = g * 64 + lane;
                    #pragma unroll
                    for (int o = 0; o < 8; ++o)
                        dot4(acc[o], x[g], S[o * 384 + ii]);
                }
                // parent feats (pre-normalized) overwrite x
                #pragma unroll
                for (int g = 0; g < 3; ++g)
                    x[g] = ld4(pfr, g * 64 + lane);
                // phase B: parent feats vs cols [768,1536)
                #pragma unroll
                for (int g = 0; g < 3; ++g) {
                    int ii = g * 64 + lane;
                    #pragma unroll
                    for (int o = 0; o < 8; ++o)
                        dot4(acc[o], x[g], S[o * 384 + 192 + ii]);
                }
                #pragma unroll
                for (int k = 32; k >= 1; k >>= 1) {
                    #pragma unroll
                    for (int o = 0; o < 8; ++o)
                        acc[o] += __shfl_xor(acc[o], k, 64);
                }
                if (lane == 0) {
                    f4 r0, r1;
                    r0.x = acc[0] + db[0]; r0.y = acc[1] + db[1];
                    r0.z = acc[2] + db[2]; r0.w = acc[3] + db[3];
                    r1.x = acc[4] + db[4]; r1.y = acc[5] + db[5];
                    r1.z = acc[6] + db[6]; r1.w = acc[7] + db[7];
                    f4* od = (f4*)(out + (size_t)NB * NS * 8 + (size_t)t * 8);
                    od[0] = r0; od[1] = r1;
                }
            } else {
                float acc[4];
                #pragma unroll
                for (int o = 0; o < 4; ++o) acc[o] = 0.f;
                #pragma unroll
                for (int g = 0; g < 3; ++g) {
                    int ii = g * 64 + lane;
                    #pragma unroll
                    for (int o = 0; o < 4; ++o)
                        dot4(acc[o], x[g], S[o * 384 + ii]);
                }
                #pragma unroll
                for (int g = 0; g < 3; ++g)
                    x[g] = ld4(pfr, g * 64 + lane);
                #pragma unroll
                for (int g = 0; g < 3; ++g) {
                    int ii = g * 64 + lane;
                    #pragma unroll
                    for (int o = 0; o < 4; ++o)
                        dot4(acc[o], x[g], S[o * 384 + 192 + ii]);
                }
                #pragma unroll
                for (int k = 32; k >= 1; k >>= 1) {
                    #pragma unroll
                    for (int o = 0; o < 4; ++o)
                        acc[o] += __shfl_xor(acc[o], k, 64);
                }
                if (lane == 0) {
                    f4 r0;
                    r0.x = acc[0] + cb[0]; r0.y = acc[1] + cb[1];
                    r0.z = acc[2] + cb[2]; r0.w = acc[3] + cb[3];
                    ((f4*)(out + (size_t)NB * NS * 16 + (size_t)t * 4))[0] = r0;
                }
            }
        }
    }
}

extern "C" void kernel_launch(void* const* d_in, const int* in_sizes, int n_in,
                              void* d_out, int out_size, void* d_ws, size_t ws_size,
                              hipStream_t stream) {
    const int* et  = (const int*)d_in[0];
    const int* ei  = (const int*)d_in[1];
    const int* ppi = (const int*)d_in[2];
    const float* sv   = (const float*)d_in[3];
    const float* temb = (const float*)d_in[4];
    const float* iemb = (const float*)d_in[5];
    const float* pemb = (const float*)d_in[6];
    const float* sw   = (const float*)d_in[7];
    const float* sb   = (const float*)d_in[8];
    const float* lng  = (const float*)d_in[9];
    const float* lnb  = (const float*)d_in[10];
    const float* pw   = (const float*)d_in[11];
    const float* pb   = (const float*)d_in[12];
    const float* dw   = (const float*)d_in[13];
    const float* db   = (const float*)d_in[14];
    const float* cw   = (const float*)d_in[15];
    const float* cbp  = (const float*)d_in[16];
    float* out = (float*)d_out;

    // ws layout:
    //   [0,2048)        table (stores seqpos+1; 0 = none)
    //   [2048,2144)     cnt[3][8]
    //   [4096,28672)    sprj (8x768 f32)
    //   [32768,+104448) wpack (6528 f4)
    //   [137216,+384KB) lists (3 x 8 x 4096 ints)
    //   [532480,+1.5MB) pfeat (512x768 f32)
    int*   table = (int*)d_ws;
    int*   cnt   = (int*)((char*)d_ws + 2048);
    float* sprj  = (float*)((char*)d_ws + 4096);
    float* wpack = (float*)((char*)d_ws + 32768);
    int*   lists = (int*)((char*)d_ws + 137216);
    float* pfeat = (float*)((char*)d_ws + 532480);

    hipMemsetAsync(d_ws, 0, 2144, stream);           // table (+1 enc) + counts
    hipMemsetAsync(d_out, 0, out_size, stream);      // masked rows = 0

    lp_pre<<<156, 256, 0, stream>>>(et, ei, sv, sw, sb, pw, dw, cw, lng, lnb,
                                    table, cnt, lists, sprj, wpack);
    lp_parent<<<128, 256, 0, stream>>>(ei, ppi, temb, iemb, pemb, lng, lnb,
                                       table, sprj, pfeat);
    lp_main<<<512, 1024, 0, stream>>>(ei, ppi, temb, iemb, pemb,
                                      pb, db, cbp,
                                      table, cnt, lists, sprj, wpack, pfeat,
                                      out);
}

// Round 10
// 139.780 us; speedup vs baseline: 1.1135x; 1.0883x over previous
//
#include <hip/hip_runtime.h>

#define NB 8
#define NS 4096
#define ND 768

// wpack layout (f4 units):
//   [0,1536)    panel weights  : o*192 + i
//   [1536,4608) dialog weights : o*384 + i  (+192 = parent half)
//   [4608,6144) char weights   : o*384 + i  (+192 = parent half)
//   [6144,6336) lng | [6336,6528) lnb
#define WPACK_F4 6528

// lp_main LDS (f4 units):
//   role 0 (panel+char): [0,1536) panel | [1536,3072) char
//   role 1 (dialog)    : [0,3072) dialog
//   both: [3072,3264) lng | [3264,3456) lnb | [3456,3648) sprj row
#define MAIN_LDS_F4 3648

typedef float4 f4;

static __device__ __forceinline__ f4 ld4(const float* __restrict__ p, int i) {
    return ((const f4*)p)[i];
}

static __device__ __forceinline__ void dot4(float& acc, const f4& a, const f4& w) {
    acc = fmaf(a.x, w.x, acc);
    acc = fmaf(a.y, w.y, acc);
    acc = fmaf(a.z, w.z, acc);
    acc = fmaf(a.w, w.w, acc);
}

// ---------------------------------------------------------------------------
// Kernel 1 (lp_pre)  — verbatim round 5 (129.9 µs session best):
//   blocks   0..127 : scatter-max parent table (last panel occurrence wins)
//   blocks 128..129 : per-batch style projection (8 waves)
//   blocks 130..155 : pack head weights + ln params into wpack (contiguous)
// ---------------------------------------------------------------------------
__global__ __launch_bounds__(256) void lp_pre(
    const int* __restrict__ et, const int* __restrict__ ei,
    const float* __restrict__ sv, const float* __restrict__ sw,
    const float* __restrict__ sb,
    const float* __restrict__ pw, const float* __restrict__ dw,
    const float* __restrict__ cw,
    const float* __restrict__ lng, const float* __restrict__ lnb,
    int* __restrict__ table, float* __restrict__ sprj,
    float* __restrict__ wpack)
{
    const int bx = blockIdx.x;
    if (bx < 128) {
        int t = bx * 256 + threadIdx.x;
        if (et[t] == 1) {
            int b = t >> 12;
            atomicMax(&table[b * 64 + ei[t]], t & (NS - 1));
        }
    } else if (bx < 130) {
        const int lane = threadIdx.x & 63;
        const int b = (bx - 128) * 4 + (threadIdx.x >> 6);   // 0..7
        const float sv0 = sv[b*4+0], sv1 = sv[b*4+1], sv2 = sv[b*4+2], sv3 = sv[b*4+3];
        #pragma unroll
        for (int g = 0; g < 3; ++g) {
            int i = g*64 + lane;
            f4 w0 = ld4(sw, i), w1 = ld4(sw, 192+i), w2 = ld4(sw, 384+i), w3 = ld4(sw, 576+i);
            f4 bb = ld4(sb, i);
            f4 r;
            r.x = bb.x + sv0*w0.x + sv1*w1.x + sv2*w2.x + sv3*w3.x;
            r.y = bb.y + sv0*w0.y + sv1*w1.y + sv2*w2.y + sv3*w3.y;
            r.z = bb.z + sv0*w0.z + sv1*w1.z + sv2*w2.z + sv3*w3.z;
            r.w = bb.w + sv0*w0.w + sv1*w1.w + sv2*w2.w + sv3*w3.w;
            ((f4*)(sprj + b*ND))[i] = r;
        }
    } else {
        const int q = (bx - 130) * 256 + threadIdx.x;   // 0..6655
        if (q >= WPACK_F4) return;
        f4 r;
        if (q < 1536) {                                  // panel: 8 x 192
            int o = q / 192, i = q - o * 192, d0 = 4 * i;
            r.x = pw[(d0+0)*8 + o];
            r.y = pw[(d0+1)*8 + o];
            r.z = pw[(d0+2)*8 + o];
            r.w = pw[(d0+3)*8 + o];
        } else if (q < 4608) {                           // dialog: 8 x 384
            int u = q - 1536;
            int o = u / 384, i = u - o * 384;
            int d0 = (i < 192) ? 4*i : 768 + 4*(i - 192);
            r.x = dw[(d0+0)*8 + o];
            r.y = dw[(d0+1)*8 + o];
            r.z = dw[(d0+2)*8 + o];
            r.w = dw[(d0+3)*8 + o];
        } else if (q < 6144) {                           // char: 4 x 384
            int u = q - 4608;
            int o = u / 384, i = u - o * 384;
            int d0 = (i < 192) ? 4*i : 768 + 4*(i - 192);
            r.x = cw[(d0+0)*4 + o];
            r.y = cw[(d0+1)*4 + o];
            r.z = cw[(d0+2)*4 + o];
            r.w = cw[(d0+3)*4 + o];
        } else if (q < 6336) {                           // lng
            r = ld4(lng, q - 6144);
        } else {                                         // lnb
            r = ld4(lnb, q - 6336);
        }
        ((f4*)wpack)[q] = r;
    }
}

// ---------------------------------------------------------------------------
// Kernel 2 (lp_parent) — verbatim round 5: one wave per (b, slot);
// NORMALIZED parent feats into pfeat[b*64+slot].
// ---------------------------------------------------------------------------
__global__ __launch_bounds__(256) void lp_parent(
    const int* __restrict__ ei, const int* __restrict__ ppi,
    const float* __restrict__ temb, const float* __restrict__ iemb,
    const float* __restrict__ pemb, const float* __restrict__ lng,
    const float* __restrict__ lnb,
    const int* __restrict__ table, const float* __restrict__ sprj,
    float* __restrict__ pfeat)
{
    const int lane = threadIdx.x & 63;
    const int slot = blockIdx.x * 4 + (threadIdx.x >> 6);   // 0..511
    const int b = slot >> 6;
    const int pp = table[slot];
    if (pp < 0) return;                                     // wave-uniform
    const int ptok = b * NS + pp;
    const int pei = ei[ptok], pppi = ppi[ptok];
    const float* ie = iemb + pei * ND;
    const float* pe = pemb + pppi * ND;
    const float* sp = sprj + b * ND;

    f4 x[3]; float s1 = 0.f, sq = 0.f;
    #pragma unroll
    for (int g = 0; g < 3; ++g) {
        int i = g*64 + lane;
        f4 a = ld4(temb + ND, i), c = ld4(ie, i), d = ld4(pe, i), s = ld4(sp, i);
        f4 v;
        v.x = a.x + c.x + d.x + s.x;
        v.y = a.y + c.y + d.y + s.y;
        v.z = a.z + c.z + d.z + s.z;
        v.w = a.w + c.w + d.w + s.w;
        x[g] = v;
        s1 += v.x + v.y + v.z + v.w;
        sq = fmaf(v.x, v.x, sq);
        sq = fmaf(v.y, v.y, sq);
        sq = fmaf(v.z, v.z, sq);
        sq = fmaf(v.w, v.w, sq);
    }
    #pragma unroll
    for (int k = 32; k >= 1; k >>= 1) {
        s1 += __shfl_xor(s1, k, 64);
        sq += __shfl_xor(sq, k, 64);
    }
    float mu = s1 * (1.f/ND);
    float rs = rsqrtf(sq * (1.f/ND) - mu * mu + 1e-5f);
    float c0 = -mu * rs;
    float* dst = pfeat + (size_t)slot * ND;
    #pragma unroll
    for (int g = 0; g < 3; ++g) {
        int i = g*64 + lane;
        f4 gg = ld4(lng, i), bb = ld4(lnb, i);
        f4 v = x[g], xn;
        xn.x = fmaf(v.x, rs, c0); v.x = fmaf(xn.x, gg.x, bb.x);
        xn.y = fmaf(v.y, rs, c0); v.y = fmaf(xn.y, gg.y, bb.y);
        xn.z = fmaf(v.z, rs, c0); v.z = fmaf(xn.z, gg.z, bb.z);
        xn.w = fmaf(v.w, rs, c0); v.w = fmaf(xn.w, gg.w, bb.w);
        ((f4*)dst)[i] = v;
    }
}

// ---------------------------------------------------------------------------
// Kernel 3 (lp_main): round-5 persistent design + pair/role split for
// 2 blocks/CU. Block pair p covers tokens [128p,128p+128); even block
// handles panel+char, odd block dialog. Each stages only its role's
// weights (58,368 B -> 2 blocks/CU -> 32 waves/CU). Waves scan their
// 8-token stripe directly (one-ahead scalar prefetch, as round 5),
// skipping non-matching tokens wave-uniformly. No lists, no atomics.
// Out is pre-zeroed, so skipped tokens need no write.
// ---------------------------------------------------------------------------
__global__ __launch_bounds__(1024) void lp_main(
    const int* __restrict__ et, const int* __restrict__ ei, const int* __restrict__ ppi,
    const float* __restrict__ temb, const float* __restrict__ iemb,
    const float* __restrict__ pemb,
    const float* __restrict__ pb, const float* __restrict__ db,
    const float* __restrict__ cb,
    const int* __restrict__ table, const float* __restrict__ sprj,
    const float* __restrict__ wpack, const float* __restrict__ pfeat,
    float* __restrict__ out)
{
    __shared__ f4 S[MAIN_LDS_F4];            // 58,368 B -> 2 blocks/CU
    const int tid = threadIdx.x;
    const int lane = tid & 63;
    const int wid = tid >> 6;                // 0..15
    const int bx = blockIdx.x;               // 0..511
    const int pair = bx >> 1;                // 0..255, 128 tokens each
    const int role = bx & 1;                 // 0: panel+char, 1: dialog
    const int b = pair >> 5;                 // 32 pairs per batch

    // ---- stage role weights + ln + this batch's style row ----
    const f4* wsrc = (const f4*)wpack;
    if (role == 0) {
        for (int i = tid; i < 1536; i += 1024) {
            S[i] = wsrc[i];                   // panel
            S[1536 + i] = wsrc[4608 + i];     // char
        }
    } else {
        for (int i = tid; i < 3072; i += 1024)
            S[i] = wsrc[1536 + i];            // dialog
    }
    if (tid < 384) S[3072 + tid] = wsrc[6144 + tid];          // lng, lnb
    if (tid < 192) S[3456 + tid] = ((const f4*)(sprj + b * ND))[tid];
    __syncthreads();

    // ---- prefetch scalars for first token ----
    int t = pair * 128 + wid;
    int type = et[t], my_ei = ei[t], my_ppi = ppi[t];

    for (int r = 0; r < 8; ++r) {
        // prefetch next token's scalars (breaks index->gather dependency)
        const int tn = t + 16;
        int type_n = 0, ei_n = 0, ppi_n = 0;
        if (r < 7) { type_n = et[tn]; ei_n = ei[tn]; ppi_n = ppi[tn]; }

        const bool mine = role ? (type == 2) : (type == 1 || type == 3);
        if (mine) {
            int pp = -1;
            if (type != 1) pp = table[b * 64 + my_ppi];   // issue early

            if (type == 1 || pp >= 0) {
                const float* te = temb + type * ND;
                const float* ie = iemb + my_ei * ND;
                const float* pe = pemb + my_ppi * ND;

                // --- own feats: embedding sum + style, single-pass stats ---
                f4 x[3];
                float s1 = 0.f, sq = 0.f;
                #pragma unroll
                for (int g = 0; g < 3; ++g) {
                    int ii = g * 64 + lane;
                    f4 a = ld4(te, ii), c = ld4(ie, ii), d = ld4(pe, ii);
                    f4 sp = S[3456 + ii];
                    f4 v;
                    v.x = a.x + c.x + d.x + sp.x;
                    v.y = a.y + c.y + d.y + sp.y;
                    v.z = a.z + c.z + d.z + sp.z;
                    v.w = a.w + c.w + d.w + sp.w;
                    x[g] = v;
                    s1 += v.x + v.y + v.z + v.w;
                    sq = fmaf(v.x, v.x, sq);
                    sq = fmaf(v.y, v.y, sq);
                    sq = fmaf(v.z, v.z, sq);
                    sq = fmaf(v.w, v.w, sq);
                }
                #pragma unroll
                for (int k = 32; k >= 1; k >>= 1) {
                    s1 += __shfl_xor(s1, k, 64);
                    sq += __shfl_xor(sq, k, 64);
                }
                float mu = s1 * (1.f / ND);
                float rs = rsqrtf(sq * (1.f / ND) - mu * mu + 1e-5f);
                float c0 = -mu * rs;
                #pragma unroll
                for (int g = 0; g < 3; ++g) {
                    int ii = g * 64 + lane;
                    f4 gg = S[3072 + ii], bb = S[3264 + ii];
                    f4 v = x[g], xn;
                    xn.x = fmaf(v.x, rs, c0); v.x = fmaf(xn.x, gg.x, bb.x);
                    xn.y = fmaf(v.y, rs, c0); v.y = fmaf(xn.y, gg.y, bb.y);
                    xn.z = fmaf(v.z, rs, c0); v.z = fmaf(xn.z, gg.z, bb.z);
                    xn.w = fmaf(v.w, rs, c0); v.w = fmaf(xn.w, gg.w, bb.w);
                    x[g] = v;
                }

                if (type == 1) {
                    float acc[8];
                    #pragma unroll
                    for (int o = 0; o < 8; ++o) acc[o] = 0.f;
                    #pragma unroll
                    for (int g = 0; g < 3; ++g) {
                        int ii = g * 64 + lane;
                        #pragma unroll
                        for (int o = 0; o < 8; ++o)
                            dot4(acc[o], x[g], S[o * 192 + ii]);
                    }
                    #pragma unroll
                    for (int k = 32; k >= 1; k >>= 1) {
                        #pragma unroll
                        for (int o = 0; o < 8; ++o)
                            acc[o] += __shfl_xor(acc[o], k, 64);
                    }
                    if (lane == 0) {
                        f4 r0, r1;
                        r0.x = acc[0] + pb[0]; r0.y = acc[1] + pb[1];
                        r0.z = acc[2] + pb[2]; r0.w = acc[3] + pb[3];
                        r1.x = acc[4] + pb[4]; r1.y = acc[5] + pb[5];
                        r1.z = acc[6] + pb[6]; r1.w = acc[7] + pb[7];
                        f4* op = (f4*)(out + (size_t)t * 8);
                        op[0] = r0; op[1] = r1;
                    }
                } else if (type == 2) {
                    const float* pfr = pfeat + (size_t)(b * 64 + my_ppi) * ND;
                    float acc[8];
                    #pragma unroll
                    for (int o = 0; o < 8; ++o) acc[o] = 0.f;
                    // phase A: own feats vs cols [0,768)
                    #pragma unroll
                    for (int g = 0; g < 3; ++g) {
                        int ii = g * 64 + lane;
                        #pragma unroll
                        for (int o = 0; o < 8; ++o)
                            dot4(acc[o], x[g], S[o * 384 + ii]);
                    }
                    // parent feats (pre-normalized) overwrite x
                    #pragma unroll
                    for (int g = 0; g < 3; ++g)
                        x[g] = ld4(pfr, g * 64 + lane);
                    // phase B: parent feats vs cols [768,1536)
                    #pragma unroll
                    for (int g = 0; g < 3; ++g) {
                        int ii = g * 64 + lane;
                        #pragma unroll
                        for (int o = 0; o < 8; ++o)
                            dot4(acc[o], x[g], S[o * 384 + 192 + ii]);
                    }
                    #pragma unroll
                    for (int k = 32; k >= 1; k >>= 1) {
                        #pragma unroll
                        for (int o = 0; o < 8; ++o)
                            acc[o] += __shfl_xor(acc[o], k, 64);
                    }
                    if (lane == 0) {
                        f4 r0, r1;
                        r0.x = acc[0] + db[0]; r0.y = acc[1] + db[1];
                        r0.z = acc[2] + db[2]; r0.w = acc[3] + db[3];
                        r1.x = acc[4] + db[4]; r1.y = acc[5] + db[5];
                        r1.z = acc[6] + db[6]; r1.w = acc[7] + db[7];
                        f4* od = (f4*)(out + (size_t)NB * NS * 8 + (size_t)t * 8);
                        od[0] = r0; od[1] = r1;
                    }
                } else {
                    const float* pfr = pfeat + (size_t)(b * 64 + my_ppi) * ND;
                    float acc[4];
                    #pragma unroll
                    for (int o = 0; o < 4; ++o) acc[o] = 0.f;
                    #pragma unroll
                    for (int g = 0; g < 3; ++g) {
                        int ii = g * 64 + lane;
                        #pragma unroll
                        for (int o = 0; o < 4; ++o)
                            dot4(acc[o], x[g], S[1536 + o * 384 + ii]);
                    }
                    #pragma unroll
                    for (int g = 0; g < 3; ++g)
                        x[g] = ld4(pfr, g * 64 + lane);
                    #pragma unroll
                    for (int g = 0; g < 3; ++g) {
                        int ii = g * 64 + lane;
                        #pragma unroll
                        for (int o = 0; o < 4; ++o)
                            dot4(acc[o], x[g], S[1536 + o * 384 + 192 + ii]);
                    }
                    #pragma unroll
                    for (int k = 32; k >= 1; k >>= 1) {
                        #pragma unroll
                        for (int o = 0; o < 4; ++o)
                            acc[o] += __shfl_xor(acc[o], k, 64);
                    }
                    if (lane == 0) {
                        f4 r0;
                        r0.x = acc[0] + cb[0]; r0.y = acc[1] + cb[1];
                        r0.z = acc[2] + cb[2]; r0.w = acc[3] + cb[3];
                        ((f4*)(out + (size_t)NB * NS * 16 + (size_t)t * 4))[0] = r0;
                    }
                }
            }
        }

        t = tn; type = type_n; my_ei = ei_n; my_ppi = ppi_n;
    }
}

extern "C" void kernel_launch(void* const* d_in, const int* in_sizes, int n_in,
                              void* d_out, int out_size, void* d_ws, size_t ws_size,
                              hipStream_t stream) {
    const int* et  = (const int*)d_in[0];
    const int* ei  = (const int*)d_in[1];
    const int* ppi = (const int*)d_in[2];
    const float* sv   = (const float*)d_in[3];
    const float* temb = (const float*)d_in[4];
    const float* iemb = (const float*)d_in[5];
    const float* pemb = (const float*)d_in[6];
    const float* sw   = (const float*)d_in[7];
    const float* sb   = (const float*)d_in[8];
    const float* lng  = (const float*)d_in[9];
    const float* lnb  = (const float*)d_in[10];
    const float* pw   = (const float*)d_in[11];
    const float* pb   = (const float*)d_in[12];
    const float* dw   = (const float*)d_in[13];
    const float* db   = (const float*)d_in[14];
    const float* cw   = (const float*)d_in[15];
    const float* cbp  = (const float*)d_in[16];
    float* out = (float*)d_out;

    // ws layout: [0,2KB) table | [4KB,28KB) sproj | [32KB,+104448B) wpack
    //            | then pfeat (512x768 f32 = 1.5MB)
    int*   table = (int*)d_ws;
    float* sprj  = (float*)((char*)d_ws + 4096);
    float* wpack = (float*)((char*)d_ws + 32768);
    float* pfeat = (float*)((char*)d_ws + 32768 + WPACK_F4 * 16);

    hipMemsetAsync(table, 0xFF, NB * 64 * sizeof(int), stream);  // all -1
    hipMemsetAsync(d_out, 0, out_size, stream);      // skipped tokens = 0

    lp_pre<<<156, 256, 0, stream>>>(et, ei, sv, sw, sb, pw, dw, cw, lng, lnb,
                                    table, sprj, wpack);
    lp_parent<<<128, 256, 0, stream>>>(ei, ppi, temb, iemb, pemb, lng, lnb,
                                       table, sprj, pfeat);
    lp_main<<<512, 1024, 0, stream>>>(et, ei, ppi, temb, iemb, pemb,
                                      pb, db, cbp,
                                      table, sprj, wpack, pfeat, out);
}